// Round 5
// baseline (165.609 us; speedup 1.0000x reference)
//
#include <hip/hip_runtime.h>

#define NEG_INF_F (-1e30f)
#define MARGIN_F 0.1f
#define TABN 4096
#define BR 128     // rows per block
#define NT 256     // threads per block

// ---- monotone float<->uint key for atomicMax on floats ----
__device__ __forceinline__ unsigned fkey(float f) {
    unsigned b = __float_as_uint(f);
    return (b & 0x80000000u) ? ~b : (b | 0x80000000u);
}
__device__ __forceinline__ float fdec(unsigned k) {
    unsigned b = (k & 0x80000000u) ? (k ^ 0x80000000u) : ~k;
    return __uint_as_float(b);
}

// ============================================================
// Kernel A: setup (1 block). id->bitmask tables, gathered qT,
// init qkeys (global max slots), accums, barrier counters.
// ============================================================
__global__ __launch_bounds__(256) void setup_kernel(
    const float* __restrict__ inputs_col,
    const int* __restrict__ targets_col,
    const int* __restrict__ qidxs,
    const int* __restrict__ pidxs,
    const int* __restrict__ nnegs,
    unsigned* __restrict__ ptab,    // [TABN]
    unsigned* __restrict__ ntab,    // [TABN]
    float* __restrict__ qT,         // [d][32] k-major
    unsigned* __restrict__ qkeys,   // [32][2]: pos,neg max keys
    float* __restrict__ accums,     // [160]
    unsigned* __restrict__ bar,     // [2]
    int d, int Q, int P, int Nn, int triplet_len)
{
    __shared__ int qmap[32];
    const int tid = threadIdx.x;

    if (tid < Q) {
        int t = targets_col[tid * triplet_len];
        int l = 0;
        for (int i = Q - 1; i >= 0; --i) if (qidxs[i] == t) l = i;  // argmax semantics
        qmap[tid] = l;
    }
    for (int i = tid; i < TABN; i += 256) { ptab[i] = 0u; ntab[i] = 0u; }
    if (tid < 2 * Q) qkeys[tid] = fkey(NEG_INF_F);
    if (tid < 160) accums[tid] = 0.f;
    if (tid < 2) bar[tid] = 0u;
    __syncthreads();

    for (int i = tid; i < Q * P; i += 256) {
        int q = i / P, k = i - q * P;
        int id = pidxs[qmap[q] * P + k];
        if ((unsigned)id < TABN) atomicOr(&ptab[id], 1u << q);
    }
    for (int i = tid; i < Q * Nn; i += 256) {
        int q = i / Nn, k = i - q * Nn;
        int id = nnegs[qmap[q] * Nn + k];
        if ((unsigned)id < TABN) atomicOr(&ntab[id], 1u << q);
    }
    for (int i = tid; i < d * Q; i += 256) {
        int dd = i >> 5, q = i & 31;    // Q == 32
        qT[i] = inputs_col[(size_t)(q * triplet_len) * d + dd];
    }
}

// ============================================================
// Manual grid barrier. Co-residency: grid=512, capacity 8
// blocks/CU (threads/LDS/VGPR all allow 8) x 256 CUs = 2048.
// ============================================================
__device__ __forceinline__ void gsync(unsigned* cnt, unsigned nblk) {
    __syncthreads();
    if (threadIdx.x == 0) {
        __threadfence();                 // release
        atomicAdd(cnt, 1u);
        while (__hip_atomic_load(cnt, __ATOMIC_RELAXED, __HIP_MEMORY_SCOPE_AGENT) < nblk)
            __builtin_amdgcn_s_sleep(2);
        __threadfence();                 // acquire
    }
    __syncthreads();
}

// ============================================================
// Fused kernel: rows stream global->reg (4-buffer pipeline),
// queries LDS-broadcast. Per-thread tile 4q x 4r.
//  phase1: dots + masked maxes -> global atomicMax qkeys[64]
//  gsync
//  phase2: thresholds from qkeys, select on register acc,
//          wave+block reduce -> atomicAdd accums[160]
//  last-block ticket -> finalize -> out[0]
// ============================================================
__global__ __launch_bounds__(NT) void fused_kernel(
    const float* __restrict__ qT,        // [128][32]
    const float* __restrict__ rows,      // [m][128]
    const int* __restrict__ targets_row,
    const unsigned* __restrict__ ptab,
    const unsigned* __restrict__ ntab,
    unsigned* __restrict__ qkeys,        // [32][2]
    float* __restrict__ accums,          // [160]
    unsigned* __restrict__ bar,          // [2]
    float* __restrict__ out,
    int m, int nb)
{
    __shared__ float qv[128][32];        // [k][q]
    __shared__ unsigned spk[32], snk[32];
    __shared__ float sthr[2][32];        // [0]=pos_max [1]=neg_max
    __shared__ float wpart[4][32][5];
    __shared__ int islast;

    const int tid = threadIdx.x;
    const int bid = blockIdx.x;
    const int j0 = bid * BR;
    const int qg = tid & 7, q0 = qg * 4;
    const int rg = tid >> 3;             // 0..31
    const int r0 = j0 + rg * 4;

    for (int i = tid; i < 128 * 32; i += NT) ((float*)qv)[i] = qT[i];
    if (tid < 32) { spk[tid] = fkey(NEG_INF_F); snk[tid] = fkey(NEG_INF_F); }

    // masks for my 4 rows (8 lanes share rg -> merged loads; tables L1-hot)
    unsigned pb[4], nbr[4];
#pragma unroll
    for (int ri = 0; ri < 4; ++ri) {
        int t = targets_row[r0 + ri];
        if ((unsigned)t < TABN) { pb[ri] = ptab[t]; nbr[ri] = ~ntab[t]; }
        else                    { pb[ri] = 0u; nbr[ri] = ~0u; }
    }

    const float* base = rows + (size_t)r0 * 128;
    float4 b0[4], b1[4], b2[4], b3[4];

#define LOADB(B, K4) { _Pragma("unroll") \
    for (int ri = 0; ri < 4; ++ri) B[ri] = *(const float4*)(base + ri * 128 + (K4) * 4); }

#define STEP(B, K4) { _Pragma("unroll") \
    for (int dk = 0; dk < 4; ++dk) { \
        float4 qf = *(const float4*)&qv[(K4) * 4 + dk][q0]; \
        _Pragma("unroll") \
        for (int qi = 0; qi < 4; ++qi) { \
            float qq = ((const float*)&qf)[qi]; \
            _Pragma("unroll") \
            for (int ri = 0; ri < 4; ++ri) \
                acc[qi][ri] = fmaf(qq, ((const float*)&B[ri])[dk], acc[qi][ri]); \
        } } }

    LOADB(b0, 0) LOADB(b1, 1) LOADB(b2, 2)

    __syncthreads();   // qv ready

    float acc[4][4];
#pragma unroll
    for (int a = 0; a < 4; ++a)
#pragma unroll
        for (int b = 0; b < 4; ++b) acc[a][b] = 0.f;

    for (int k4 = 0; k4 < 32; k4 += 4) {
        if (k4 + 3 < 32) LOADB(b3, k4 + 3)
        STEP(b0, k4 + 0)
        if (k4 + 4 < 32) LOADB(b0, k4 + 4)
        STEP(b1, k4 + 1)
        if (k4 + 5 < 32) LOADB(b1, k4 + 5)
        STEP(b2, k4 + 2)
        if (k4 + 6 < 32) LOADB(b2, k4 + 6)
        STEP(b3, k4 + 3)
    }

    // block masked maxes -> LDS -> global atomicMax
#pragma unroll
    for (int qi = 0; qi < 4; ++qi) {
        const int q = q0 + qi;
        float pmax = NEG_INF_F, nmax = NEG_INF_F;
#pragma unroll
        for (int r = 0; r < 4; ++r) {
            if ((pb[r] >> q) & 1u)  pmax = fmaxf(pmax, acc[qi][r]);
            if ((nbr[r] >> q) & 1u) nmax = fmaxf(nmax, acc[qi][r]);
        }
#pragma unroll
        for (int off = 32; off >= 8; off >>= 1) {
            pmax = fmaxf(pmax, __shfl_down(pmax, off));
            nmax = fmaxf(nmax, __shfl_down(nmax, off));
        }
        if ((tid & 63) < 8) {
            atomicMax(&spk[q], fkey(pmax));
            atomicMax(&snk[q], fkey(nmax));
        }
    }
    __syncthreads();
    if (tid < 64) {
        int side = tid >> 5, q = tid & 31;
        atomicMax(&qkeys[q * 2 + side], side ? snk[q] : spk[q]);
    }

    gsync(&bar[0], (unsigned)nb);

    // ---- phase 2: thresholds ----
    if (tid < 64) {
        int side = tid >> 5, q = tid & 31;
        sthr[side][q] = fdec(qkeys[q * 2 + side]);
    }
    __syncthreads();

    const int wave = tid >> 6, lane = tid & 63;
#pragma unroll
    for (int qi = 0; qi < 4; ++qi) {
        const int q = q0 + qi;
        const float posThr = sthr[1][q] + MARGIN_F;               // s < neg_max + margin
        const float negThr = fmaxf(0.4f, sthr[0][q]) - MARGIN_F;  // s > max(0.4,pos_max) - margin
        float ps = 0.f, pc = 0.f, ns = 0.f, nc = 0.f, pmc = 0.f;
#pragma unroll
        for (int r = 0; r < 4; ++r) {
            float s = acc[qi][r];
            unsigned pm = (pb[r] >> q) & 1u;
            unsigned nm = (nbr[r] >> q) & 1u;
            pmc += (float)pm;
            if (pm && s < posThr) { ps += 1.f - s; pc += 1.f; }
            if (nm && s > negThr) { ns += s;       nc += 1.f; }
        }
#pragma unroll
        for (int off = 32; off >= 8; off >>= 1) {
            ps  += __shfl_down(ps, off);
            pc  += __shfl_down(pc, off);
            ns  += __shfl_down(ns, off);
            nc  += __shfl_down(nc, off);
            pmc += __shfl_down(pmc, off);
        }
        if (lane < 8) {
            wpart[wave][lane * 4 + qi][0] = ps;
            wpart[wave][lane * 4 + qi][1] = pc;
            wpart[wave][lane * 4 + qi][2] = ns;
            wpart[wave][lane * 4 + qi][3] = nc;
            wpart[wave][lane * 4 + qi][4] = pmc;
        }
    }
    __syncthreads();
    if (tid < 160) {
        float v = 0.f;
#pragma unroll
        for (int w = 0; w < 4; ++w) v += wpart[w][tid / 5][tid % 5];
        atomicAdd(&accums[tid], v);
    }

    // ---- last-block finalize ----
    __syncthreads();
    if (tid == 0) {
        __threadfence();
        unsigned old = atomicAdd(&bar[1], 1u);
        islast = (old == (unsigned)(nb - 1)) ? 1 : 0;
    }
    __syncthreads();
    if (islast) {
        if (tid == 0) __threadfence();
        __syncthreads();
        if (tid < 64) {
            float v = 0.f;
            if (tid < 32) {
                float psv = accums[tid * 5 + 0];
                float pcv = accums[tid * 5 + 1];
                float nsv = accums[tid * 5 + 2];
                float ncv = accums[tid * 5 + 3];
                float pmc = accums[tid * 5 + 4];
                float pl = (pcv > 0.f) ? psv / pcv : 0.f;
                float nl = (ncv > 0.f) ? nsv / ncv : 0.f;
                v = (pmc > 0.f) ? (pl + nl) : 0.f;
            }
#pragma unroll
            for (int off = 32; off; off >>= 1) v += __shfl_down(v, off);
            if (tid == 0) out[0] = v / 32.0f;
        }
    }
}

// ============================================================
extern "C" void kernel_launch(void* const* d_in, const int* in_sizes, int n_in,
                              void* d_out, int out_size, void* d_ws, size_t ws_size,
                              hipStream_t stream)
{
    const float* inputs_col = (const float*)d_in[0];
    const float* inputs_row = (const float*)d_in[1];
    const int* targets_col  = (const int*)d_in[2];
    const int* targets_row  = (const int*)d_in[3];
    const int* qidxs        = (const int*)d_in[4];
    const int* pidxs        = (const int*)d_in[5];
    const int* nnegs        = (const int*)d_in[6];

    const int n  = in_sizes[2];
    int m        = in_sizes[3];
    const int Q  = in_sizes[4];            // 32
    const int P  = in_sizes[5] / Q;        // 10
    const int Nn = in_sizes[6] / Q;        // 25
    const int d  = in_sizes[0] / n;        // 128
    const int triplet_len = n / Q;         // 12

    int nb = (m + BR - 1) / BR;            // 512

    char* ws = (char*)d_ws;
    size_t off = 0;
    unsigned* ptab  = (unsigned*)(ws + off); off += (size_t)TABN * 4;
    unsigned* ntab  = (unsigned*)(ws + off); off += (size_t)TABN * 4;
    float* qT       = (float*)(ws + off);    off += (size_t)d * Q * 4;
    unsigned* qkeys = (unsigned*)(ws + off); off += (size_t)Q * 2 * 4;
    float* accums   = (float*)(ws + off);    off += (size_t)160 * 4;
    unsigned* bar   = (unsigned*)(ws + off); off += 2 * 4;
    float* out      = (float*)d_out;

    setup_kernel<<<1, 256, 0, stream>>>(inputs_col, targets_col, qidxs, pidxs, nnegs,
                                        ptab, ntab, qT, qkeys, accums, bar,
                                        d, Q, P, Nn, triplet_len);

    fused_kernel<<<nb, NT, 0, stream>>>(qT, inputs_row, targets_row, ptab, ntab,
                                        qkeys, accums, bar, out, m, nb);
}